// Round 4
// baseline (142.096 us; speedup 1.0000x reference)
//
#include <hip/hip_runtime.h>
#include <math.h>

// Problem constants: B=64, IN=1024, OUT=512, T=512, V_TH=1, TAU=16
#define BATCH   64
#define INS     1024
#define OUTS    512
#define TSTEPS  512
#define TAUF    16.0f

// ---------------------------------------------------------------------------
// Fused pre-kernel: blocks [0,128) tiled weight transpose w[OUT,IN]->wT[IN,OUT];
// blocks [128,192) per-batch spike prep + counting sort by activation time.
//   alpha(t-s) = e^{-t/tau} * (t*A + C) for t > s,
//   A = exp(1 + s/tau)/tau,  C = -s*A,  t_on = floor(s)+1 in [1,256].
// Record per spike (sorted by t_on): {A, (float)idx, -s, (float)t_on}
//   (.zw pair = what pass 2 needs -> single b64 LDS read)
// ---------------------------------------------------------------------------
#define TT 64
#define NTRANS ((INS / TT) * (OUTS / TT))   // 128 transpose blocks

__global__ __launch_bounds__(256) void pre_kernel(
        const float* __restrict__ w, float* __restrict__ wT,
        const float* __restrict__ in_spike, float4* __restrict__ spk) {
    __shared__ float tile[TT][TT + 1];
    __shared__ int hist[257];
    __shared__ int cursor[257];
    __shared__ int scanbuf[256];

    if (blockIdx.x < NTRANS) {
        const int i0 = (blockIdx.x & (INS / TT - 1)) * TT;
        const int o0 = (blockIdx.x / (INS / TT)) * TT;
        const int c  = threadIdx.x & 63;
        const int r  = threadIdx.x >> 6;
#pragma unroll
        for (int rr = r; rr < TT; rr += 4)
            tile[rr][c] = w[(o0 + rr) * INS + i0 + c];
        __syncthreads();
#pragma unroll
        for (int rr = r; rr < TT; rr += 4)
            wT[(i0 + rr) * OUTS + o0 + c] = tile[c][rr];
        return;
    }

    const int b = blockIdx.x - NTRANS;
    for (int k = threadIdx.x; k < 257; k += 256) hist[k] = 0;
    __syncthreads();

    float sv[INS / 256];
    int   tv[INS / 256];
#pragma unroll
    for (int j = 0; j < INS / 256; ++j) {
        int i = threadIdx.x + j * 256;
        float s = in_spike[b * INS + i];
        sv[j] = s;
        int t = (int)floorf(s) + 1;
        t = t < 1 ? 1 : (t > 256 ? 256 : t);
        tv[j] = t;
        atomicAdd(&hist[t], 1);
    }
    __syncthreads();

    const int tid = threadIdx.x;
    int v = hist[tid + 1];
    scanbuf[tid] = v;
    __syncthreads();
#pragma unroll
    for (int off = 1; off < 256; off <<= 1) {
        int add = (tid >= off) ? scanbuf[tid - off] : 0;
        __syncthreads();
        scanbuf[tid] += add;
        __syncthreads();
    }
    cursor[tid + 1] = scanbuf[tid] - v;
    __syncthreads();

#pragma unroll
    for (int j = 0; j < INS / 256; ++j) {
        int i = threadIdx.x + j * 256;
        int t = tv[j];
        int pos = atomicAdd(&cursor[t], 1);
        float A = expf(fmaf(sv[j], 1.0f / TAUF, 1.0f)) * (1.0f / TAUF);
        spk[b * INS + pos] = make_float4(A, (float)i, -sv[j], (float)t);
    }
}

// ---------------------------------------------------------------------------
// Scan kernel.  Block = (b, 16 outputs), 512 threads: threadIdx.x = output
// lane (16), threadIdx.y = time-sorted chunk g of 32 (32 spikes each).
// Pass 1: chunk-partial (S wA, S wC), stashing wa_k = w*A_k in 32 registers.
// LDS exclusive scan over g.  Pass 2: re-walk own chunk GATHER-FREE (register
// stash + b64 LDS re-read of (-s, t_on)), interleaving threshold checks over
// the owned time range — ranges partition the time axis, so atomicMin over
// per-chunk first crossings is exact.  V(t)>=1 <=> fma(t,SA,SC) >= exp(t/tau).
// Grid = 64 * 32 = 2048 blocks; __launch_bounds__(512,6) -> 3 blocks/CU.
// ---------------------------------------------------------------------------
#define OL 16            // outputs per block
#define G  32            // chunks per output
#define CH (INS / G)     // 32 spikes per chunk

__global__ __launch_bounds__(OL * G, 6) void spike_scan_kernel(
        const float4* __restrict__ spk, const float* __restrict__ wT,
        float* __restrict__ out) {
    const int b = blockIdx.x;
    const int x = threadIdx.x;           // 0..15 output lane
    const int g = threadIdx.y;           // 0..31 chunk
    const int o = blockIdx.y * OL + x;
    const int tid = g * OL + x;

    __shared__ float4 sspk[INS];         // 16 KB
    __shared__ float  sE[TSTEPS];        // 2 KB: exp(t/tau)
    __shared__ float  psA[G][OL];        // 2 KB
    __shared__ float  psC[G][OL];        // 2 KB
    __shared__ int    sFirst[OL];        // 64 B

    const float4* bspk = spk + b * INS;
    for (int k = tid; k < INS; k += OL * G) sspk[k] = bspk[k];
    for (int t = tid; t < TSTEPS; t += OL * G) sE[t] = expf((float)t * (1.0f / TAUF));
    if (tid < OL) sFirst[x] = TSTEPS;
    __syncthreads();

    const int k0 = g * CH;
    const float2* sspk2 = (const float2*)sspk;   // [2*k+1] = (-s, t_on)

    // ---- pass 1: chunk partials; stash wa_k in registers ----
    float was[CH];
    float pA = 0.f, pC = 0.f;
#pragma unroll
    for (int kk = 0; kk < CH; kk += 4) {
        float4 p0 = sspk[k0 + kk + 0];
        float4 p1 = sspk[k0 + kk + 1];
        float4 p2 = sspk[k0 + kk + 2];
        float4 p3 = sspk[k0 + kk + 3];
        float w0 = wT[(int)p0.y * OUTS + o];
        float w1 = wT[(int)p1.y * OUTS + o];
        float w2 = wT[(int)p2.y * OUTS + o];
        float w3 = wT[(int)p3.y * OUTS + o];
        float a0 = w0 * p0.x, a1 = w1 * p1.x, a2 = w2 * p2.x, a3 = w3 * p3.x;
        was[kk + 0] = a0; was[kk + 1] = a1; was[kk + 2] = a2; was[kk + 3] = a3;
        pA += a0; pC = fmaf(a0, p0.z, pC);
        pA += a1; pC = fmaf(a1, p1.z, pC);
        pA += a2; pC = fmaf(a2, p2.z, pC);
        pA += a3; pC = fmaf(a3, p3.z, pC);
    }
    psA[g][x] = pA; psC[g][x] = pC;
    __syncthreads();

    // ---- exclusive scan over the G chunks ----
    float SA = 0.f, SC = 0.f;
    for (int j = 0; j < g; ++j) { SA += psA[j][x]; SC += psC[j][x]; }

    int tcur = (int)sspk[k0].w;
    const int tend = (g == G - 1) ? TSTEPS : (int)sspk2[2 * (k0 + CH) + 1].y;

    int first = TSTEPS;

#define ADVANCE_TO(TK)                                                        \
    while (tcur + 4 <= (TK)) {                                                \
        float e0 = sE[tcur], e1 = sE[tcur + 1], e2 = sE[tcur + 2],            \
              e3 = sE[tcur + 3];                                              \
        float tf = (float)tcur;                                               \
        bool c0 = fmaf(tf,        SA, SC) >= e0;                              \
        bool c1 = fmaf(tf + 1.f,  SA, SC) >= e1;                              \
        bool c2 = fmaf(tf + 2.f,  SA, SC) >= e2;                              \
        bool c3 = fmaf(tf + 3.f,  SA, SC) >= e3;                              \
        if (c0 | c1 | c2 | c3) {                                              \
            first = c0 ? tcur : c1 ? tcur + 1 : c2 ? tcur + 2 : tcur + 3;     \
            goto scan_done;                                                   \
        }                                                                     \
        tcur += 4;                                                            \
    }                                                                         \
    while (tcur < (TK)) {                                                     \
        if (fmaf((float)tcur, SA, SC) >= sE[tcur]) {                          \
            first = tcur; goto scan_done;                                     \
        }                                                                     \
        ++tcur;                                                               \
    }

    // skip pass 2 if our time range is empty or an earlier crossing exists
    if (tcur >= tend || sFirst[x] <= tcur) goto scan_done;

    // ---- pass 2: gather-free re-walk with threshold checks ----
#pragma unroll
    for (int kk = 0; kk < CH; kk += 4) {
        float2 q0 = sspk2[2 * (k0 + kk + 0) + 1];
        float2 q1 = sspk2[2 * (k0 + kk + 1) + 1];
        float2 q2 = sspk2[2 * (k0 + kk + 2) + 1];
        float2 q3 = sspk2[2 * (k0 + kk + 3) + 1];
        int tk;
        tk = (int)q0.y; ADVANCE_TO(tk);
        SA += was[kk + 0]; SC = fmaf(was[kk + 0], q0.x, SC);
        tk = (int)q1.y; ADVANCE_TO(tk);
        SA += was[kk + 1]; SC = fmaf(was[kk + 1], q1.x, SC);
        tk = (int)q2.y; ADVANCE_TO(tk);
        SA += was[kk + 2]; SC = fmaf(was[kk + 2], q2.x, SC);
        tk = (int)q3.y; ADVANCE_TO(tk);
        SA += was[kk + 3]; SC = fmaf(was[kk + 3], q3.x, SC);
    }
    ADVANCE_TO(tend);
#undef ADVANCE_TO

scan_done:
    if (first < TSTEPS) atomicMin(&sFirst[x], first);
    __syncthreads();
    if (tid < OL) out[b * OUTS + o] = (float)sFirst[x];
}

// ---------------------------------------------------------------------------
extern "C" void kernel_launch(void* const* d_in, const int* in_sizes, int n_in,
                              void* d_out, int out_size, void* d_ws, size_t ws_size,
                              hipStream_t stream) {
    const float* in_spike = (const float*)d_in[0];   // [B, IN] fp32
    const float* weight   = (const float*)d_in[1];   // [OUT, IN] fp32
    float* out = (float*)d_out;                      // [B, OUT] fp32

    float*  wT  = (float*)d_ws;                                        // 2 MB
    float4* spk = (float4*)((char*)d_ws + (size_t)INS * OUTS * sizeof(float)); // 1 MB

    pre_kernel<<<NTRANS + BATCH, 256, 0, stream>>>(weight, wT, in_spike, spk);
    spike_scan_kernel<<<dim3(BATCH, OUTS / OL), dim3(OL, G), 0, stream>>>(spk, wT, out);
}